// Round 2
// baseline (761.244 us; speedup 1.0000x reference)
//
#include <hip/hip_runtime.h>
#include <cstdint>
#include <cstddef>

// GAT layer, N=8192, F_in=512, F_out=64, fp32, int32 adjacency.
// Fused flash-style, 3 kernels:
//   k_wh     : Wh = h@W ; wh1 = Wh.a1 ; wh2 = Wh.a2 ; atomicMax(enc(max wh2))
//   k_attend : rows x j-stream: p = adj ? exp(lrelu(wh1_i+wh2_j) - M_i) : 0
//              (M_i = lrelu(wh1_i + max wh2) >= true rowmax, softmax shift-inv)
//              o_i += p*Wh_j ; l_i += p   (4-way j-split partials)
//   k_merge  : out = sum(o)/sum(l)

#define GAT_N    8192
#define GAT_FIN  512
#define GAT_F    64
#define TJ       64
#define JSPLIT   4
#define JCHUNK   (GAT_N / JSPLIT)     // 2048
#define NTILES   (JCHUNK / TJ)        // 32

__device__ __forceinline__ float lrelu(float x) { return fmaxf(x, 0.2f * x); }

__device__ __forceinline__ unsigned enc_f32(float f) {
    unsigned b = __float_as_uint(f);
    return b ^ ((b & 0x80000000u) ? 0xFFFFFFFFu : 0x80000000u);
}
__device__ __forceinline__ float dec_f32(unsigned u) {
    return __uint_as_float(u ^ ((u & 0x80000000u) ? 0x80000000u : 0xFFFFFFFFu));
}

__device__ __forceinline__ void gload_lds16(const void* g, void* l) {
    __builtin_amdgcn_global_load_lds(
        (const __attribute__((address_space(1))) void*)g,
        (__attribute__((address_space(3))) void*)l, 16, 0, 0);
}

// ---------------------------------------------------------------- kernel 1
// grid 1024, block 256: 8 rows/block, thread = (kh, row, f4); k-split 2.
__global__ __launch_bounds__(256) void k_wh(
    const float* __restrict__ h, const float* __restrict__ W,
    const float* __restrict__ a,
    float* __restrict__ Wh, float* __restrict__ wh1, float* __restrict__ wh2,
    unsigned int* __restrict__ mw2)
{
    __shared__ float sh[8 * 516];
    __shared__ float sacc[8 * 64];
    __shared__ unsigned int smax[8];
    const int tid = threadIdx.x;
    const size_t r0 = (size_t)blockIdx.x * 8;

    const float4* __restrict__ hsrc = (const float4*)(h + r0 * GAT_FIN);
#pragma unroll
    for (int c = 0; c < 4; ++c) {
        int idx = tid + c * 256;              // 1024 float4 = 8 rows x 128
        int row = idx >> 7, c4 = idx & 127;
        *(float4*)&sh[row * 516 + c4 * 4] = hsrc[idx];
    }
    __syncthreads();

    const int f4  = (tid & 15) * 4;
    const int row = (tid >> 4) & 7;
    const int kh  = tid >> 7;                 // k-half
    float4 acc = {0.f, 0.f, 0.f, 0.f};
    const float* shr = &sh[row * 516 + kh * 256];
    const float* wb  = &W[(size_t)(kh * 256) * GAT_F + f4];
#pragma unroll 4
    for (int k = 0; k < 256; ++k) {
        float4 wv = *(const float4*)&wb[(size_t)k * GAT_F];
        float hv = shr[k];
        acc.x = fmaf(hv, wv.x, acc.x);
        acc.y = fmaf(hv, wv.y, acc.y);
        acc.z = fmaf(hv, wv.z, acc.z);
        acc.w = fmaf(hv, wv.w, acc.w);
    }
    if (kh == 1) *(float4*)&sacc[(row * 16 + (tid & 15)) * 4] = acc;
    __syncthreads();
    if (kh == 0) {
        float4 o = *(const float4*)&sacc[(row * 16 + (tid & 15)) * 4];
        acc.x += o.x; acc.y += o.y; acc.z += o.z; acc.w += o.w;
        *(float4*)&Wh[(r0 + row) * GAT_F + f4] = acc;
        float4 a1 = *(const float4*)&a[f4];
        float4 a2 = *(const float4*)&a[GAT_F + f4];
        float pa = acc.x*a1.x + acc.y*a1.y + acc.z*a1.z + acc.w*a1.w;
        float pb = acc.x*a2.x + acc.y*a2.y + acc.z*a2.z + acc.w*a2.w;
#pragma unroll
        for (int m = 1; m < 16; m <<= 1) {
            pa += __shfl_xor(pa, m);
            pb += __shfl_xor(pb, m);
        }
        if ((tid & 15) == 0) {
            wh1[r0 + row] = pa;
            wh2[r0 + row] = pb;
            smax[row] = enc_f32(pb);
        }
    }
    __syncthreads();
    if (tid == 0) {
        unsigned m = smax[0];
#pragma unroll
        for (int r = 1; r < 8; ++r) m = max(m, smax[r]);
        atomicMax(mw2, m);
    }
}

// ---------------------------------------------------------------- kernel 2
// grid (256, 4), block 256 (4 waves). Block: 32 rows x 2048-j chunk.
// Wave owns 8 rows. Per 64-j tile:
//   phase A (lane=(rA,jsub)): p for rows rA,rA+4, 4 j's -> sP (wave-private)
//   phase B (lane=(jb,fb)):   o[8 rows][8 f] partial over jb's 8-j strip
// sWh XOR-swizzled at 16B granules: stored g' = gf ^ (j>>3); staged via
// global_load_lds with pre-swizzled SOURCE address (LDS dest linear).
__global__ __launch_bounds__(256, 4) void k_attend(
    const int* __restrict__ adj, const float* __restrict__ Wh,
    const float* __restrict__ wh1, const float* __restrict__ wh2,
    const unsigned int* __restrict__ mw2,
    float* __restrict__ po, float* __restrict__ pl)
{
    __shared__ float sWh[2][TJ * GAT_F];      // 2 x 16 KB, swizzled
    __shared__ float sP[4][8][TJ];            // per-wave P, 8 KB

    const int tid  = threadIdx.x;
    const int w    = tid >> 6;
    const int lane = tid & 63;
    const int rw   = blockIdx.x * 32 + w * 8;
    const int j0   = blockIdx.y * JCHUNK;

    const float Mw2 = dec_f32(*mw2);

    // phase A mapping
    const int rA   = lane >> 4;
    const int jsub = (lane & 15) * 4;
    const float a0 = wh1[rw + rA];
    const float a4 = wh1[rw + rA + 4];
    const float M0 = lrelu(a0 + Mw2);
    const float M4 = lrelu(a4 + Mw2);

    // phase B mapping
    const int jb = lane >> 3, fb = lane & 7;
    const int wrow0 = jb * 8 * GAT_F;                 // float idx of strip base
    const int g0o = (((2 * fb)    ) ^ jb) * 4;        // swizzled granule offsets
    const int g1o = (((2 * fb) + 1) ^ jb) * 4;

    // staging source byte-offsets (pre-swizzled), constant across tiles
    int soff[4];
#pragma unroll
    for (int c = 0; c < 4; ++c) {
        int G = tid + c * 256;                // dest granule (linear)
        int j = G >> 4, gp = G & 15;
        soff[c] = (j * 16 + (gp ^ (j >> 3))) * 16;
    }
    const int ldsoff = w * 64 * 16;           // wave-uniform dest byte base

    const char* wsrcb = (const char*)(Wh + (size_t)j0 * GAT_F);

    // adj/wh2 pointers
    const int* ap0 = adj + (size_t)(rw + rA) * GAT_N + j0 + jsub;
    const int* ap4 = ap0 + (size_t)4 * GAT_N;
    const float* b4p = wh2 + j0 + jsub;

    // ---- prologue: stage tile 0, load tile-0 adj/wh2
    {
        char* dstb = (char*)sWh[0];
#pragma unroll
        for (int c = 0; c < 4; ++c)
            gload_lds16(wsrcb + soff[c], dstb + ldsoff + c * 256 * 16);
    }
    int4  adjc0 = *(const int4*)ap0;
    int4  adjc4 = *(const int4*)ap4;
    float4 b4c  = *(const float4*)b4p;

    float4 oacc[8][2] = {};
    float l0 = 0.f, l4 = 0.f;

    for (int t = 0; t < NTILES; ++t) {
        const int cur = t & 1;
        __syncthreads();                      // sWh[cur] staged & visible

        // ---- issue next-tile loads (consumed after the NEXT barrier)
        const int nstep = (t + 1 < NTILES) ? (t + 1) * TJ : t * TJ;
        int4  adjn0 = *(const int4*)(ap0 + nstep);
        int4  adjn4 = *(const int4*)(ap4 + nstep);
        float4 b4n  = *(const float4*)(b4p + nstep);
        if (t + 1 < NTILES) {
            const char* src = wsrcb + (size_t)(t + 1) * (TJ * GAT_F * 4);
            char* dstb = (char*)sWh[cur ^ 1];
#pragma unroll
            for (int c = 0; c < 4; ++c)
                gload_lds16(src + soff[c], dstb + ldsoff + c * 256 * 16);
        }

        // ---- phase A: p from prefetched regs -> sP
        float4 p0, p4;
        p0.x = adjc0.x > 0 ? __expf(lrelu(a0 + b4c.x) - M0) : 0.f;
        p0.y = adjc0.y > 0 ? __expf(lrelu(a0 + b4c.y) - M0) : 0.f;
        p0.z = adjc0.z > 0 ? __expf(lrelu(a0 + b4c.z) - M0) : 0.f;
        p0.w = adjc0.w > 0 ? __expf(lrelu(a0 + b4c.w) - M0) : 0.f;
        p4.x = adjc4.x > 0 ? __expf(lrelu(a4 + b4c.x) - M4) : 0.f;
        p4.y = adjc4.y > 0 ? __expf(lrelu(a4 + b4c.y) - M4) : 0.f;
        p4.z = adjc4.z > 0 ? __expf(lrelu(a4 + b4c.z) - M4) : 0.f;
        p4.w = adjc4.w > 0 ? __expf(lrelu(a4 + b4c.w) - M4) : 0.f;
        l0 += p0.x + p0.y + p0.z + p0.w;
        l4 += p4.x + p4.y + p4.z + p4.w;
        *(float4*)&sP[w][rA][jsub]     = p0;
        *(float4*)&sP[w][rA + 4][jsub] = p4;
        __builtin_amdgcn_wave_barrier();      // A-writes before B-reads (same wave)

        // ---- phase B: o[8][8] += P(strip) @ sWh
        const float* wb0 = &sWh[cur][wrow0 + g0o];
        const float* wb1 = &sWh[cur][wrow0 + g1o];
        const float* pbse = &sP[w][0][jb * 8];
#pragma unroll
        for (int j = 0; j < 8; ++j) {
            float4 wv0 = *(const float4*)&wb0[j * GAT_F];
            float4 wv1 = *(const float4*)&wb1[j * GAT_F];
#pragma unroll
            for (int r = 0; r < 8; ++r) {
                float p = pbse[r * TJ + j];
                oacc[r][0].x = fmaf(p, wv0.x, oacc[r][0].x);
                oacc[r][0].y = fmaf(p, wv0.y, oacc[r][0].y);
                oacc[r][0].z = fmaf(p, wv0.z, oacc[r][0].z);
                oacc[r][0].w = fmaf(p, wv0.w, oacc[r][0].w);
                oacc[r][1].x = fmaf(p, wv1.x, oacc[r][1].x);
                oacc[r][1].y = fmaf(p, wv1.y, oacc[r][1].y);
                oacc[r][1].z = fmaf(p, wv1.z, oacc[r][1].z);
                oacc[r][1].w = fmaf(p, wv1.w, oacc[r][1].w);
            }
        }

        // rotate prefetched regs
        adjc0 = adjn0; adjc4 = adjn4; b4c = b4n;
    }

    // ---- epilogue
#pragma unroll
    for (int m = 1; m < 16; m <<= 1) {
        l0 += __shfl_xor(l0, m);
        l4 += __shfl_xor(l4, m);
    }
    if ((lane & 15) == 0) {
        pl[(size_t)blockIdx.y * GAT_N + rw + rA]     = l0;
        pl[(size_t)blockIdx.y * GAT_N + rw + rA + 4] = l4;
    }

    const size_t obase = ((size_t)blockIdx.y * GAT_N + rw) * GAT_F + fb * 8;
#pragma unroll
    for (int r = 0; r < 8; ++r) {
#pragma unroll
        for (int hh = 0; hh < 2; ++hh) {
            float4 v = oacc[r][hh];
#pragma unroll
            for (int m = 8; m <= 32; m <<= 1) {
                v.x += __shfl_xor(v.x, m);
                v.y += __shfl_xor(v.y, m);
                v.z += __shfl_xor(v.z, m);
                v.w += __shfl_xor(v.w, m);
            }
            if (jb == 0)
                *(float4*)&po[obase + (size_t)r * GAT_F + hh * 4] = v;
        }
    }
}

// ---------------------------------------------------------------- kernel 3
__global__ __launch_bounds__(256) void k_merge(
    const float* __restrict__ po, const float* __restrict__ pl,
    float* __restrict__ out)
{
    const int idx = blockIdx.x * 256 + threadIdx.x;   // = i*64 + f
    const int i = idx >> 6;
    float s = 0.f, ls = 0.f;
#pragma unroll
    for (int y = 0; y < JSPLIT; ++y) {
        s  += po[(size_t)y * GAT_N * GAT_F + idx];
        ls += pl[(size_t)y * GAT_N + i];
    }
    out[idx] = s / ls;
}

// ---------------------------------------------------------------- launch
extern "C" void kernel_launch(void* const* d_in, const int* in_sizes, int n_in,
                              void* d_out, int out_size, void* d_ws, size_t ws_size,
                              hipStream_t stream) {
    (void)in_sizes; (void)n_in; (void)out_size; (void)ws_size;
    const float* h   = (const float*)d_in[0];
    const int*   adj = (const int*)d_in[1];
    const float* W   = (const float*)d_in[2];
    const float* a   = (const float*)d_in[3];
    float* out = (float*)d_out;

    float* ws  = (float*)d_ws;
    float* Wh  = ws;                          // 524288
    float* wh1 = ws + 524288;                 // 8192
    float* wh2 = ws + 532480;                 // 8192
    unsigned int* mw2 = (unsigned int*)(ws + 540672);  // 1 (encoded max)
    float* po  = ws + 548864;                 // 4*8192*64 = 2097152
    float* pl  = ws + 2646016;                // 4*8192

    hipMemsetAsync(mw2, 0, 4, stream);        // enc: 0 < every real value
    k_wh    <<<GAT_N / 8, 256, 0, stream>>>(h, W, a, Wh, wh1, wh2, mw2);
    k_attend<<<dim3(GAT_N / 32, JSPLIT), 256, 0, stream>>>(adj, Wh, wh1, wh2, mw2, po, pl);
    k_merge <<<GAT_N * GAT_F / 256, 256, 0, stream>>>(po, pl, out);
}

// Round 3
// 459.550 us; speedup vs baseline: 1.6565x; 1.6565x over previous
//
#include <hip/hip_runtime.h>
#include <cstdint>
#include <cstddef>

// GAT layer, N=8192, F_in=512, F_out=64, fp32, int32 adjacency.
// Fused flash-style, 3 kernels:
//   k_wh     : Wh = h@W ; wh1 = Wh.a1 ; wh2 = Wh.a2 ; atomicMax(enc(max wh2))
//              (W staged in LDS chunks via global_load_lds, h broadcast via L1)
//   k_attend : rows x j-stream: p = adj ? exp(lrelu(wh1_i+wh2_j) - M_i) : 0
//              (M_i = lrelu(wh1_i + max wh2) >= true rowmax, softmax shift-inv)
//              o_i += p*Wh_j ; l_i += p   (4-way j-split partials)
//   k_merge  : out = sum(o)/sum(l)
//
// R2 lesson: __launch_bounds__(256,4) capped VGPR at 64 -> oacc spilled to
// scratch (585 MB WRITE_SIZE). Now (256,2): 2 blocks/CU, ~170 VGPR, no spill.

#define GAT_N    8192
#define GAT_FIN  512
#define GAT_F    64
#define TJ       64
#define JSPLIT   4
#define JCHUNK   (GAT_N / JSPLIT)     // 2048
#define NTILES   (JCHUNK / TJ)        // 32

__device__ __forceinline__ float lrelu(float x) { return fmaxf(x, 0.2f * x); }

__device__ __forceinline__ unsigned enc_f32(float f) {
    unsigned b = __float_as_uint(f);
    return b ^ ((b & 0x80000000u) ? 0xFFFFFFFFu : 0x80000000u);
}
__device__ __forceinline__ float dec_f32(unsigned u) {
    return __uint_as_float(u ^ ((u & 0x80000000u) ? 0x80000000u : 0xFFFFFFFFu));
}

__device__ __forceinline__ void gload_lds16(const void* g, void* l) {
    __builtin_amdgcn_global_load_lds(
        (const __attribute__((address_space(1))) void*)g,
        (__attribute__((address_space(3))) void*)l, 16, 0, 0);
}

// ---------------------------------------------------------------- kernel 1
// grid 512, block 256: 16 rows/block, thread = (rp 0..15, f4 0..15).
// W staged in LDS 128-k chunks (2x32 KB double-buffered); h rows via L1
// (16 lanes broadcast the same h[row][k] quad).
__global__ __launch_bounds__(256) void k_wh(
    const float* __restrict__ h, const float* __restrict__ W,
    const float* __restrict__ a,
    float* __restrict__ Wh, float* __restrict__ wh1, float* __restrict__ wh2,
    unsigned int* __restrict__ mw2)
{
    __shared__ float sW[2][128 * GAT_F];      // 2 x 32 KB
    __shared__ unsigned int smax[16];
    const int tid = threadIdx.x;
    const int w   = tid >> 6;
    const size_t r0 = (size_t)blockIdx.x * 16;
    const int rp = tid >> 4;
    const int f4 = (tid & 15) * 4;

    const char* wsrc = (const char*)W;
    {   // stage chunk 0 (linear: reads are row-broadcast, conflict-free)
        char* dst = (char*)sW[0];
#pragma unroll
        for (int i = 0; i < 8; ++i)
            gload_lds16(wsrc + (size_t)(tid + i * 256) * 16,
                        dst + (size_t)(w * 64 + i * 256) * 16);
    }

    const float* ha = h + (r0 + rp) * GAT_FIN;
    float4 acc = {0.f, 0.f, 0.f, 0.f};

    for (int c = 0; c < 4; ++c) {
        __syncthreads();                      // chunk c staged & visible
        if (c + 1 < 4) {
            const char* src = wsrc + (size_t)(c + 1) * (128 * GAT_F * 4);
            char* dst = (char*)sW[(c + 1) & 1];
#pragma unroll
            for (int i = 0; i < 8; ++i)
                gload_lds16(src + (size_t)(tid + i * 256) * 16,
                            dst + (size_t)(w * 64 + i * 256) * 16);
        }
        const float* wc = sW[c & 1];
#pragma unroll 4
        for (int k4 = 0; k4 < 32; ++k4) {
            float4 hv = *(const float4*)&ha[c * 128 + k4 * 4];
            const float* hvf = (const float*)&hv;
#pragma unroll
            for (int kk = 0; kk < 4; ++kk) {
                float4 wv = *(const float4*)&wc[(k4 * 4 + kk) * GAT_F + f4];
                acc.x = fmaf(hvf[kk], wv.x, acc.x);
                acc.y = fmaf(hvf[kk], wv.y, acc.y);
                acc.z = fmaf(hvf[kk], wv.z, acc.z);
                acc.w = fmaf(hvf[kk], wv.w, acc.w);
            }
        }
    }

    *(float4*)&Wh[(r0 + rp) * GAT_F + f4] = acc;

    float4 a1 = *(const float4*)&a[f4];
    float4 a2 = *(const float4*)&a[GAT_F + f4];
    float pa = acc.x*a1.x + acc.y*a1.y + acc.z*a1.z + acc.w*a1.w;
    float pb = acc.x*a2.x + acc.y*a2.y + acc.z*a2.z + acc.w*a2.w;
#pragma unroll
    for (int m = 1; m < 16; m <<= 1) {
        pa += __shfl_xor(pa, m);
        pb += __shfl_xor(pb, m);
    }
    if ((tid & 15) == 0) {
        wh1[r0 + rp] = pa;
        wh2[r0 + rp] = pb;
        smax[rp] = enc_f32(pb);
    }
    __syncthreads();
    if (tid == 0) {
        unsigned m = smax[0];
#pragma unroll
        for (int r = 1; r < 16; ++r) m = max(m, smax[r]);
        atomicMax(mw2, m);
    }
}

// ---------------------------------------------------------------- kernel 2
// grid (256, 4), block 256 (4 waves). Block: 32 rows x 2048-j chunk.
// Wave owns 8 rows. Per 64-j tile:
//   phase A (lane=(rA,jsub)): p for rows rA,rA+4, 4 j's -> sP (wave-private)
//   phase B (lane=(jb,fb)):   o[8 rows][8 f] partial over jb's 8-j strip,
//            register-blocked: preload 8 wv float4 per j-half, p via b128.
// sWh XOR-swizzled at 16B granules (g' = gf ^ (j>>3)); staged via
// global_load_lds with pre-swizzled SOURCE address (LDS dest linear).
__global__ __launch_bounds__(256, 2) void k_attend(
    const int* __restrict__ adj, const float* __restrict__ Wh,
    const float* __restrict__ wh1, const float* __restrict__ wh2,
    const unsigned int* __restrict__ mw2,
    float* __restrict__ po, float* __restrict__ pl)
{
    __shared__ float sWh[2][TJ * GAT_F];      // 2 x 16 KB, swizzled
    __shared__ float sP[4][8][TJ];            // per-wave P, 8 KB

    const int tid  = threadIdx.x;
    const int w    = tid >> 6;
    const int lane = tid & 63;
    const int rw   = blockIdx.x * 32 + w * 8;
    const int j0   = blockIdx.y * JCHUNK;

    const float Mw2 = dec_f32(*mw2);

    // phase A mapping
    const int rA   = lane >> 4;
    const int jsub = (lane & 15) * 4;
    const float a0 = wh1[rw + rA];
    const float a4 = wh1[rw + rA + 4];
    const float M0 = lrelu(a0 + Mw2);
    const float M4 = lrelu(a4 + Mw2);

    // phase B mapping
    const int jb = lane >> 3, fb = lane & 7;
    const int wrow0 = jb * 8 * GAT_F;                 // strip base (floats)
    const int g0o = (((2 * fb)    ) ^ jb) * 4;        // swizzled granules
    const int g1o = (((2 * fb) + 1) ^ jb) * 4;

    // staging source byte-offsets (pre-swizzled), constant across tiles
    int soff[4];
#pragma unroll
    for (int c = 0; c < 4; ++c) {
        int G = tid + c * 256;                // dest granule (linear)
        int j = G >> 4, gp = G & 15;
        soff[c] = (j * 16 + (gp ^ (j >> 3))) * 16;
    }
    const int ldsoff = w * 64 * 16;           // wave-uniform dest byte base

    const char* wsrcb = (const char*)(Wh + (size_t)j0 * GAT_F);

    const int* ap0 = adj + (size_t)(rw + rA) * GAT_N + j0 + jsub;
    const int* ap4 = ap0 + (size_t)4 * GAT_N;
    const float* b4p = wh2 + j0 + jsub;

    // ---- prologue: stage tile 0, load tile-0 adj/wh2
    {
        char* dstb = (char*)sWh[0];
#pragma unroll
        for (int c = 0; c < 4; ++c)
            gload_lds16(wsrcb + soff[c], dstb + ldsoff + c * 256 * 16);
    }
    int4  adjc0 = *(const int4*)ap0;
    int4  adjc4 = *(const int4*)ap4;
    float4 b4c  = *(const float4*)b4p;

    float4 oacc[8][2] = {};
    float l0 = 0.f, l4 = 0.f;

    for (int t = 0; t < NTILES; ++t) {
        const int cur = t & 1;
        __syncthreads();                      // sWh[cur] staged & visible

        // ---- issue next-tile loads (consumed after the NEXT barrier)
        const int nstep = (t + 1 < NTILES) ? (t + 1) * TJ : t * TJ;
        int4  adjn0 = *(const int4*)(ap0 + nstep);
        int4  adjn4 = *(const int4*)(ap4 + nstep);
        float4 b4n  = *(const float4*)(b4p + nstep);
        if (t + 1 < NTILES) {
            const char* src = wsrcb + (size_t)(t + 1) * (TJ * GAT_F * 4);
            char* dstb = (char*)sWh[cur ^ 1];
#pragma unroll
            for (int c = 0; c < 4; ++c)
                gload_lds16(src + soff[c], dstb + ldsoff + c * 256 * 16);
        }

        // ---- phase A: p from prefetched regs -> sP
        float4 p0, p4;
        p0.x = adjc0.x > 0 ? __expf(lrelu(a0 + b4c.x) - M0) : 0.f;
        p0.y = adjc0.y > 0 ? __expf(lrelu(a0 + b4c.y) - M0) : 0.f;
        p0.z = adjc0.z > 0 ? __expf(lrelu(a0 + b4c.z) - M0) : 0.f;
        p0.w = adjc0.w > 0 ? __expf(lrelu(a0 + b4c.w) - M0) : 0.f;
        p4.x = adjc4.x > 0 ? __expf(lrelu(a4 + b4c.x) - M4) : 0.f;
        p4.y = adjc4.y > 0 ? __expf(lrelu(a4 + b4c.y) - M4) : 0.f;
        p4.z = adjc4.z > 0 ? __expf(lrelu(a4 + b4c.z) - M4) : 0.f;
        p4.w = adjc4.w > 0 ? __expf(lrelu(a4 + b4c.w) - M4) : 0.f;
        l0 += p0.x + p0.y + p0.z + p0.w;
        l4 += p4.x + p4.y + p4.z + p4.w;
        *(float4*)&sP[w][rA][jsub]     = p0;
        *(float4*)&sP[w][rA + 4][jsub] = p4;
        __builtin_amdgcn_wave_barrier();      // A-writes before B-reads (same wave)

        // ---- phase B: oacc[8][2] += P(strip) @ sWh, register-blocked
        const float* swc = sWh[cur];
        const float* pb  = &sP[w][0][jb * 8];
#pragma unroll
        for (int jh = 0; jh < 2; ++jh) {
            float4 wv0[4], wv1[4];
#pragma unroll
            for (int jj = 0; jj < 4; ++jj) {
                const int jr = wrow0 + (jh * 4 + jj) * GAT_F;
                wv0[jj] = *(const float4*)&swc[jr + g0o];
                wv1[jj] = *(const float4*)&swc[jr + g1o];
            }
#pragma unroll
            for (int r = 0; r < 8; ++r) {
                float4 pq = *(const float4*)&pb[r * TJ + jh * 4];
                const float* pf = (const float*)&pq;
#pragma unroll
                for (int jj = 0; jj < 4; ++jj) {
                    oacc[r][0].x = fmaf(pf[jj], wv0[jj].x, oacc[r][0].x);
                    oacc[r][0].y = fmaf(pf[jj], wv0[jj].y, oacc[r][0].y);
                    oacc[r][0].z = fmaf(pf[jj], wv0[jj].z, oacc[r][0].z);
                    oacc[r][0].w = fmaf(pf[jj], wv0[jj].w, oacc[r][0].w);
                    oacc[r][1].x = fmaf(pf[jj], wv1[jj].x, oacc[r][1].x);
                    oacc[r][1].y = fmaf(pf[jj], wv1[jj].y, oacc[r][1].y);
                    oacc[r][1].z = fmaf(pf[jj], wv1[jj].z, oacc[r][1].z);
                    oacc[r][1].w = fmaf(pf[jj], wv1[jj].w, oacc[r][1].w);
                }
            }
        }

        adjc0 = adjn0; adjc4 = adjn4; b4c = b4n;
    }

    // ---- epilogue
#pragma unroll
    for (int m = 1; m < 16; m <<= 1) {
        l0 += __shfl_xor(l0, m);
        l4 += __shfl_xor(l4, m);
    }
    if ((lane & 15) == 0) {
        pl[(size_t)blockIdx.y * GAT_N + rw + rA]     = l0;
        pl[(size_t)blockIdx.y * GAT_N + rw + rA + 4] = l4;
    }

    const size_t obase = ((size_t)blockIdx.y * GAT_N + rw) * GAT_F + fb * 8;
#pragma unroll
    for (int r = 0; r < 8; ++r) {
#pragma unroll
        for (int hh = 0; hh < 2; ++hh) {
            float4 v = oacc[r][hh];
#pragma unroll
            for (int m = 8; m <= 32; m <<= 1) {
                v.x += __shfl_xor(v.x, m);
                v.y += __shfl_xor(v.y, m);
                v.z += __shfl_xor(v.z, m);
                v.w += __shfl_xor(v.w, m);
            }
            if (jb == 0)
                *(float4*)&po[obase + (size_t)r * GAT_F + hh * 4] = v;
        }
    }
}

// ---------------------------------------------------------------- kernel 3
__global__ __launch_bounds__(256) void k_merge(
    const float* __restrict__ po, const float* __restrict__ pl,
    float* __restrict__ out)
{
    const int idx = blockIdx.x * 256 + threadIdx.x;   // = i*64 + f
    const int i = idx >> 6;
    float s = 0.f, ls = 0.f;
#pragma unroll
    for (int y = 0; y < JSPLIT; ++y) {
        s  += po[(size_t)y * GAT_N * GAT_F + idx];
        ls += pl[(size_t)y * GAT_N + i];
    }
    out[idx] = s / ls;
}

// ---------------------------------------------------------------- launch
extern "C" void kernel_launch(void* const* d_in, const int* in_sizes, int n_in,
                              void* d_out, int out_size, void* d_ws, size_t ws_size,
                              hipStream_t stream) {
    (void)in_sizes; (void)n_in; (void)out_size; (void)ws_size;
    const float* h   = (const float*)d_in[0];
    const int*   adj = (const int*)d_in[1];
    const float* W   = (const float*)d_in[2];
    const float* a   = (const float*)d_in[3];
    float* out = (float*)d_out;

    float* ws  = (float*)d_ws;
    float* Wh  = ws;                          // 524288
    float* wh1 = ws + 524288;                 // 8192
    float* wh2 = ws + 532480;                 // 8192
    unsigned int* mw2 = (unsigned int*)(ws + 540672);  // 1 (encoded max)
    float* po  = ws + 548864;                 // 4*8192*64 = 2097152
    float* pl  = ws + 2646016;                // 4*8192

    hipMemsetAsync(mw2, 0, 4, stream);        // enc: 0 < every real value
    k_wh    <<<GAT_N / 16, 256, 0, stream>>>(h, W, a, Wh, wh1, wh2, mw2);
    k_attend<<<dim3(GAT_N / 32, JSPLIT), 256, 0, stream>>>(adj, Wh, wh1, wh2, mw2, po, pl);
    k_merge <<<GAT_N * GAT_F / 256, 256, 0, stream>>>(po, pl, out);
}

// Round 7
// 427.439 us; speedup vs baseline: 1.7809x; 1.0751x over previous
//
#include <hip/hip_runtime.h>
#include <cstdint>
#include <cstddef>

// GAT layer, N=8192, F_in=512, F_out=64, fp32, int32 adjacency.
//   k_wh     : Wh = h@W ; wh1/wh2 projections ; global max(wh2) via atomicMax ;
//              WhT_hi/WhT_lo = transposed 2-way bf16 split of Wh ([64 f][8192 j])
//   k_attend : per 16-row wave, stream 64-j tiles: p = adj ? exp(lrelu(.)-Mi) : 0
//              p kept in registers in MFMA A-frag layout; PV via 3x
//              mfma_f32_16x16x32_bf16 per (kstep,fblock): Ph*Whi + Pl*Whi + Ph*Wlo
//              (2-way bf16 split both sides -> fp32-level accuracy, ~2^-16 rel)
//   k_merge  : out = sum(o)/sum(l)  over JSPLIT partials
//
// R3 lesson: fp32 VALU PV has a ~100us floor (512 fmac/lane/tile); matrix pipe
// takes it to ~0, leaving adj streaming (268MB, ~140MB post-L3) as the bound.

#define GAT_N    8192
#define GAT_FIN  512
#define GAT_F    64
#define TJ       64
#define JSPLIT   4
#define JCHUNK   (GAT_N / JSPLIT)     // 2048
#define NTILES   (JCHUNK / TJ)        // 32

typedef __attribute__((ext_vector_type(8))) short short8;
typedef __attribute__((ext_vector_type(4))) float f32x4;

__device__ __forceinline__ float lrelu(float x) { return fmaxf(x, 0.2f * x); }

__device__ __forceinline__ unsigned enc_f32(float f) {
    unsigned b = __float_as_uint(f);
    return b ^ ((b & 0x80000000u) ? 0xFFFFFFFFu : 0x80000000u);
}
__device__ __forceinline__ float dec_f32(unsigned u) {
    return __uint_as_float(u ^ ((u & 0x80000000u) ? 0x80000000u : 0xFFFFFFFFu));
}
// truncation bf16 split (p >= 0 here, residual exact-capturable)
__device__ __forceinline__ short f2bf_trunc(float f) {
    return (short)(__float_as_uint(f) >> 16);
}
__device__ __forceinline__ float bfhi(float f) {
    return __uint_as_float(__float_as_uint(f) & 0xFFFF0000u);
}

__device__ __forceinline__ void gload_lds16(const void* g, void* l) {
    __builtin_amdgcn_global_load_lds(
        (const __attribute__((address_space(1))) void*)g,
        (__attribute__((address_space(3))) void*)l, 16, 0, 0);
}

// ---------------------------------------------------------------- kernel 1
// grid 512, block 256: 16 rows/block, thread = (rp 0..15, f4 0..15).
// W staged in LDS 64-k chunks (2x16 KB dbuf); emits wh1/wh2/max and the
// transposed bf16 split WhT_hi/lo via a small LDS transpose.
__global__ __launch_bounds__(256) void k_wh(
    const float* __restrict__ h, const float* __restrict__ W,
    const float* __restrict__ a,
    float* __restrict__ wh1, float* __restrict__ wh2,
    unsigned int* __restrict__ mw2,
    unsigned short* __restrict__ whtHi, unsigned short* __restrict__ whtLo)
{
    __shared__ float sW[2][64 * GAT_F];       // 2 x 16 KB
    __shared__ unsigned short sTh[GAT_F][16]; // 2 KB
    __shared__ unsigned short sTl[GAT_F][16]; // 2 KB
    __shared__ unsigned int smax[16];
    const int tid = threadIdx.x;
    const size_t r0 = (size_t)blockIdx.x * 16;
    const int rp = tid >> 4;
    const int f4 = (tid & 15) * 4;

    const char* wsrc = (const char*)W;
    {   // stage chunk 0 (linear; reads below are broadcast, conflict-free)
        char* dst = (char*)sW[0];
#pragma unroll
        for (int c = 0; c < 4; ++c)
            gload_lds16(wsrc + (size_t)(tid + c * 256) * 16,
                        dst + (size_t)(tid + c * 256) * 16);
    }

    const float* ha = h + (r0 + rp) * GAT_FIN;
    float4 acc = {0.f, 0.f, 0.f, 0.f};

    for (int ck = 0; ck < 8; ++ck) {
        __syncthreads();
        if (ck + 1 < 8) {
            const char* src = wsrc + (size_t)(ck + 1) * 16384;
            char* dst = (char*)sW[(ck + 1) & 1];
#pragma unroll
            for (int c = 0; c < 4; ++c)
                gload_lds16(src + (size_t)(tid + c * 256) * 16,
                            dst + (size_t)(tid + c * 256) * 16);
        }
        const float* wcp = sW[ck & 1];
#pragma unroll 4
        for (int k4 = 0; k4 < 16; ++k4) {
            float4 hv = *(const float4*)&ha[ck * 64 + k4 * 4];
            const float* hvf = (const float*)&hv;
#pragma unroll
            for (int kk = 0; kk < 4; ++kk) {
                float4 wv = *(const float4*)&wcp[(k4 * 4 + kk) * GAT_F + f4];
                acc.x = fmaf(hvf[kk], wv.x, acc.x);
                acc.y = fmaf(hvf[kk], wv.y, acc.y);
                acc.z = fmaf(hvf[kk], wv.z, acc.z);
                acc.w = fmaf(hvf[kk], wv.w, acc.w);
            }
        }
    }

    // wh1/wh2 projections (reduce over f within 16-lane groups)
    float4 a1 = *(const float4*)&a[f4];
    float4 a2 = *(const float4*)&a[GAT_F + f4];
    float pa = acc.x*a1.x + acc.y*a1.y + acc.z*a1.z + acc.w*a1.w;
    float pb = acc.x*a2.x + acc.y*a2.y + acc.z*a2.z + acc.w*a2.w;
#pragma unroll
    for (int m = 1; m < 16; m <<= 1) {
        pa += __shfl_xor(pa, m);
        pb += __shfl_xor(pb, m);
    }
    if ((tid & 15) == 0) {
        wh1[r0 + rp] = pa;
        wh2[r0 + rp] = pb;
        smax[rp] = enc_f32(pb);
    }

    // bf16 split -> LDS transpose buffers
    const float* af = (const float*)&acc;
#pragma unroll
    for (int e = 0; e < 4; ++e) {
        float v = af[e];
        sTh[f4 + e][rp] = (unsigned short)f2bf_trunc(v);
        sTl[f4 + e][rp] = (unsigned short)f2bf_trunc(v - bfhi(v));
    }
    __syncthreads();

    {   // write out WhT rows: thread = (f 0..63, rq 0..3) -> 4 bf16 = 8B
        const int f = tid >> 2, rq = tid & 3;
        uint2 vh = *(const uint2*)&sTh[f][rq * 4];
        uint2 vl = *(const uint2*)&sTl[f][rq * 4];
        *(uint2*)&whtHi[(size_t)f * GAT_N + r0 + rq * 4] = vh;
        *(uint2*)&whtLo[(size_t)f * GAT_N + r0 + rq * 4] = vl;
    }
    if (tid == 0) {
        unsigned m = smax[0];
#pragma unroll
        for (int r = 1; r < 16; ++r) m = max(m, smax[r]);
        atomicMax(mw2, m);
    }
}

// ---------------------------------------------------------------- kernel 2
// grid (128, 4), block 256 (4 waves x 16 rows = 64 rows/block).
// Per 64-j tile: phase A computes p in registers laid out as the MFMA
// A-fragment (lane = (row l&15, jgroup l>>4), 8 j per kstep); PV is 24
// mfma_f32_16x16x32_bf16 (2 ksteps x 4 fblocks x 3 split terms).
// WhT tiles (bf16, [f][j]) staged 2x(hi+lo) double-buffered, XOR-swizzled
// via pre-swizzled global_load_lds SOURCE; ds_read_b128 B-frags conflict-free.
__global__ __launch_bounds__(256, 3) void k_attend(
    const int* __restrict__ adj,
    const unsigned short* __restrict__ whtHi,
    const unsigned short* __restrict__ whtLo,
    const float* __restrict__ wh1, const float* __restrict__ wh2,
    const unsigned int* __restrict__ mw2,
    float* __restrict__ po, float* __restrict__ pl)
{
    __shared__ char sB[2][16384];             // [buf][hi 8KB | lo 8KB]

    const int tid  = threadIdx.x;
    const int w    = tid >> 6;
    const int lane = tid & 63;
    const int fl   = lane & 15;
    const int jg   = lane >> 4;
    const int rw   = blockIdx.x * 64 + w * 16;
    const int j0   = blockIdx.y * JCHUNK;

    const float Mw2 = dec_f32(*mw2);
    const float ai  = wh1[rw + fl];           // this lane's row
    const float Mi  = lrelu(ai + Mw2);        // safe rowmax bound

    // staging: dest granule G (16B) at [f=G>>3][g=G&7]; source pre-swizzled
    const char* ssrc[4]; int sdst[4];
#pragma unroll
    for (int c = 0; c < 4; ++c) {
        int G = tid + (c & 1) * 256;
        int f = G >> 3, g = G & 7;
        const unsigned short* base = (c < 2) ? whtHi : whtLo;
        ssrc[c] = (const char*)(base + (size_t)f * GAT_N + j0 + ((g ^ (f & 7)) * 8));
        sdst[c] = ((c < 2) ? 0 : 8192) + G * 16;
    }

    // B-frag byte offsets within a buffer (nb folds into +nb*2048 immediate)
    const int off0 = fl * 128 + (((0 * 4 + jg) ^ (fl & 7)) * 16);
    const int off1 = fl * 128 + (((1 * 4 + jg) ^ (fl & 7)) * 16);

    const int*   ap = adj + (size_t)(rw + fl) * GAT_N + j0 + jg * 8;
    const float* wp = wh2 + j0 + jg * 8;

    // ---- prologue: stage tile 0, prefetch tile-0 adj/wh2 (q = kstep*2+half)
    {
#pragma unroll
        for (int c = 0; c < 4; ++c)
            gload_lds16(ssrc[c], (char*)sB[0] + sdst[c]);
    }
    int4 ac[4]; float4 wc[4];
#pragma unroll
    for (int q = 0; q < 4; ++q) {
        int o = (q >> 1) * 32 + (q & 1) * 4;
        ac[q] = *(const int4*)(ap + o);
        wc[q] = *(const float4*)(wp + o);
    }

    f32x4 acc[4] = {};                        // C tiles for 4 f-blocks
    float psum = 0.f;

    for (int t = 0; t < NTILES; ++t) {
        const int cur = t & 1;
        __syncthreads();                      // sB[cur] staged & visible

        // issue next-tile staging + reg prefetch
        if (t + 1 < NTILES) {
#pragma unroll
            for (int c = 0; c < 4; ++c)
                gload_lds16(ssrc[c] + (size_t)(t + 1) * 128,
                            (char*)sB[cur ^ 1] + sdst[c]);
        }
        const int tn = (t + 1 < NTILES) ? t + 1 : t;
        int4 an[4]; float4 wn[4];
#pragma unroll
        for (int q = 0; q < 4; ++q) {
            int o = tn * TJ + (q >> 1) * 32 + (q & 1) * 4;
            an[q] = *(const int4*)(ap + o);
            wn[q] = *(const float4*)(wp + o);
        }

        const char* sbc = sB[cur];
#pragma unroll
        for (int s = 0; s < 2; ++s) {         // kstep: j = s*32 + jg*8 + e
            float pv[8];
#pragma unroll
            for (int hh = 0; hh < 2; ++hh) {
                const int*   avi = (const int*)&ac[s * 2 + hh];
                const float* bvf = (const float*)&wc[s * 2 + hh];
#pragma unroll
                for (int e = 0; e < 4; ++e) {
                    float sc = lrelu(ai + bvf[e]);
                    float pe = __expf(sc - Mi);
                    pv[hh * 4 + e] = (avi[e] > 0) ? pe : 0.f;
                }
            }
            short8 ph, plo;
#pragma unroll
            for (int e = 0; e < 8; ++e) {
                psum  += pv[e];
                ph[e]  = f2bf_trunc(pv[e]);
                plo[e] = f2bf_trunc(pv[e] - bfhi(pv[e]));
            }
            const int offs = s ? off1 : off0;
#pragma unroll
            for (int nb = 0; nb < 4; ++nb) {
                short8 bh = *(const short8*)(sbc + offs + nb * 2048);
                short8 bl = *(const short8*)(sbc + 8192 + offs + nb * 2048);
                acc[nb] = __builtin_amdgcn_mfma_f32_16x16x32_bf16(ph,  bh, acc[nb], 0, 0, 0);
                acc[nb] = __builtin_amdgcn_mfma_f32_16x16x32_bf16(plo, bh, acc[nb], 0, 0, 0);
                acc[nb] = __builtin_amdgcn_mfma_f32_16x16x32_bf16(ph,  bl, acc[nb], 0, 0, 0);
            }
        }
#pragma unroll
        for (int q = 0; q < 4; ++q) { ac[q] = an[q]; wc[q] = wn[q]; }
    }

    // ---- epilogue: row sums (4 jg-groups hold partial sums per row)
    psum += __shfl_xor(psum, 16);
    psum += __shfl_xor(psum, 32);
    if (lane < 16)
        pl[(size_t)blockIdx.y * GAT_N + rw + lane] = psum;

    // C layout (m89): col = lane&15 (=f within block), row = (lane>>4)*4 + reg
    const size_t ob = ((size_t)blockIdx.y * GAT_N + rw + jg * 4) * GAT_F + fl;
#pragma unroll
    for (int nb = 0; nb < 4; ++nb) {
#pragma unroll
        for (int r = 0; r < 4; ++r)
            po[ob + (size_t)r * GAT_F + nb * 16] = acc[nb][r];
    }
}

// ---------------------------------------------------------------- kernel 3
__global__ __launch_bounds__(256) void k_merge(
    const float* __restrict__ po, const float* __restrict__ pl,
    float* __restrict__ out)
{
    const int idx = blockIdx.x * 256 + threadIdx.x;   // = i*64 + f
    const int i = idx >> 6;
    float s = 0.f, ls = 0.f;
#pragma unroll
    for (int y = 0; y < JSPLIT; ++y) {
        s  += po[(size_t)y * GAT_N * GAT_F + idx];
        ls += pl[(size_t)y * GAT_N + i];
    }
    out[idx] = s / ls;
}

// ---------------------------------------------------------------- launch
extern "C" void kernel_launch(void* const* d_in, const int* in_sizes, int n_in,
                              void* d_out, int out_size, void* d_ws, size_t ws_size,
                              hipStream_t stream) {
    (void)in_sizes; (void)n_in; (void)out_size; (void)ws_size;
    const float* h   = (const float*)d_in[0];
    const int*   adj = (const int*)d_in[1];
    const float* W   = (const float*)d_in[2];
    const float* a   = (const float*)d_in[3];
    float* out = (float*)d_out;

    char* wsb = (char*)d_ws;
    float*          wh1   = (float*)(wsb);                    // 32 KB
    float*          wh2   = (float*)(wsb + 32768);            // 32 KB
    unsigned int*   mw2   = (unsigned int*)(wsb + 65536);     // 4 B
    unsigned short* whtHi = (unsigned short*)(wsb + 131072);  // 1 MB
    unsigned short* whtLo = (unsigned short*)(wsb + 1179648); // 1 MB
    float*          po    = (float*)(wsb + 2228224);          // 8 MB
    float*          pl    = (float*)(wsb + 10616832);         // 128 KB

    hipMemsetAsync(mw2, 0, 4, stream);        // enc: 0 < every real value
    k_wh    <<<GAT_N / 16, 256, 0, stream>>>(h, W, a, wh1, wh2, mw2, whtHi, whtLo);
    k_attend<<<dim3(GAT_N / 64, JSPLIT), 256, 0, stream>>>(adj, whtHi, whtLo,
                                                           wh1, wh2, mw2, po, pl);
    k_merge <<<GAT_N * GAT_F / 256, 256, 0, stream>>>(po, pl, out);
}